// Round 4
// baseline (192.273 us; speedup 1.0000x reference)
//
#include <hip/hip_runtime.h>

typedef short short8 __attribute__((ext_vector_type(8)));
typedef float f32x4 __attribute__((ext_vector_type(4)));

#define NB 8            // real batch rows per block
#define H 128
#define TSTEPS 64
#define PRED 32
#define XROWSTRIDE 260  // 64*4 + 4 pad floats
#define NWAVE 8

// MFMA D rows are l4*4+reg. We keep regs {0,1} as the real rows so the
// epilogue is 2 values/lane with NO divergence. LDS rows {0,1,4,5,8,9,12,13}
// are real; g(r) = (r>>2)*2 + (r&1) maps LDS row -> real row 0..7;
// inverse ldsrow(i) = (i>>1)*4 + (i&1). Garbage LDS rows stay finite (zeros /
// duplicated x) and are never read back as real data.

__device__ __forceinline__ unsigned short bf16_rne(float f) {
  unsigned u = __builtin_bit_cast(unsigned, f);
  u += 0x7fffu + ((u >> 16) & 1u);
  return (unsigned short)(u >> 16);
}
__device__ __forceinline__ float bf16_f(unsigned short s) {
  unsigned u = ((unsigned)s) << 16;
  return __builtin_bit_cast(float, u);
}
// R2's tanh (verified 4.88e-4 end-to-end). Do NOT swap for raw v_exp/v_rcp —
// that variant cost 43x accuracy over the 96-step recurrence (R3 post-mortem).
__device__ __forceinline__ float tanh_fast(float v) {
  v = fminf(9.0f, fmaxf(-9.0f, v));
  float e = __expf(2.0f * v);
  return __fdividef(e - 1.0f, e + 1.0f);
}

__device__ __forceinline__ void split_frag(const f32x4& a, const f32x4& b,
                                           short8& hi, short8& lo) {
  #pragma unroll
  for (int e = 0; e < 4; ++e) {
    unsigned short h1 = bf16_rne(a[e]);
    hi[e] = (short)h1;
    lo[e] = (short)bf16_rne(a[e] - bf16_f(h1));
    unsigned short h2 = bf16_rne(b[e]);
    hi[e + 4] = (short)h2;
    lo[e + 4] = (short)bf16_rne(b[e] - bf16_f(h2));
  }
}

// One RNN step for this wave's 16-col tile. acc0 pre-initialized with
// bias + input term. Epilogue only for regs 0..1 (the real rows).
__device__ __forceinline__ void rnn_step(
    const short* __restrict__ hc_hi, const short* __restrict__ hc_lo,
    short* __restrict__ hn_hi, short* __restrict__ hn_lo,
    const short8 whi[4], const short8 wlo[4],
    f32x4 acc0, int l4, int ln, int jj, float hv[2]) {
  short8 ah[4], al[4];
  #pragma unroll
  for (int kt = 0; kt < 4; ++kt) {
    const int idx = ln * H + ((((kt << 2) + l4) ^ ln) << 3);  // swizzled
    ah[kt] = *(const short8*)&hc_hi[idx];
    al[kt] = *(const short8*)&hc_lo[idx];
  }
  f32x4 accb = {0.f, 0.f, 0.f, 0.f};
  f32x4 accc = {0.f, 0.f, 0.f, 0.f};
  #pragma unroll
  for (int kt = 0; kt < 4; ++kt) {  // 3 independent 4-deep MFMA chains
    acc0 = __builtin_amdgcn_mfma_f32_16x16x32_bf16(ah[kt], whi[kt], acc0, 0, 0, 0);
    accb = __builtin_amdgcn_mfma_f32_16x16x32_bf16(ah[kt], wlo[kt], accb, 0, 0, 0);
    accc = __builtin_amdgcn_mfma_f32_16x16x32_bf16(al[kt], whi[kt], accc, 0, 0, 0);
  }
  #pragma unroll
  for (int reg = 0; reg < 2; ++reg) {   // real rows only
    const int r = l4 * 4 + reg;
    float v = tanh_fast(acc0[reg] + accb[reg] + accc[reg]);
    hv[reg] = v;
    unsigned short p = bf16_rne(v);
    const int idx = r * H + (((jj >> 3) ^ r) << 3) + (jj & 7);
    hn_hi[idx] = (short)p;
    hn_lo[idx] = (short)bf16_rne(v - bf16_f(p));
  }
}

__global__ __launch_bounds__(512, 4) void traj_kernel(
    const float* __restrict__ x,
    const float* __restrict__ eWih, const float* __restrict__ eWhh,
    const float* __restrict__ ebih, const float* __restrict__ ebhh,
    const float* __restrict__ dWih, const float* __restrict__ dWhh,
    const float* __restrict__ dbih, const float* __restrict__ dbhh,
    const float* __restrict__ fcW, const float* __restrict__ fcb,
    float* __restrict__ out)
{
  __shared__ __align__(16) float x_lds[16 * XROWSTRIDE];   // 16.6 KB
  __shared__ __align__(16) short h_hi[2][16 * H];          // 8 KB (swizzled)
  __shared__ __align__(16) short h_lo[2][16 * H];          // 8 KB
  __shared__ float inp_lds[16][4];
  __shared__ float part[2][NWAVE][16][3];

  const int tid = threadIdx.x;
  const int lane = tid & 63;
  const int w = tid >> 6;
  const int l4 = lane >> 4;
  const int ln = lane & 15;
  const int r0 = blockIdx.x * NB;
  const int jj = w * 16 + ln;

  // ---- stage x: 16 LDS rows (real rows + duplicates for garbage rows) ----
  #pragma unroll
  for (int s = 0; s < 6; ++s) {
    int flat = tid + s * 512;          // = ldsrow*192 + rem
    int r = flat / 192;
    int rem = flat - r * 192;
    int t = rem / 3;
    int i = rem - t * 3;
    int g = (r >> 2) * 2 + (r & 1);
    x_lds[r * XROWSTRIDE + t * 4 + i] = x[(size_t)(r0 + g) * 192 + rem];
  }
  // ---- zero BOTH h buffers (garbage LDS rows must stay finite forever) ----
  #pragma unroll
  for (int s = 0; s < 4; ++s) {
    h_hi[0][tid + s * 512] = 0; h_hi[1][tid + s * 512] = 0;
    h_lo[0][tid + s * 512] = 0; h_lo[1][tid + s * 512] = 0;
  }

  // ---- encoder weights (row jj of eWhh), split hi/lo ----
  short8 whi[4], wlo[4];
  #pragma unroll
  for (int kt = 0; kt < 4; ++kt) {
    const float* p = eWhh + jj * H + kt * 32 + l4 * 8;
    split_frag(*(const f32x4*)p, *(const f32x4*)(p + 4), whi[kt], wlo[kt]);
  }
  float bias = ebih[jj] + ebhh[jj];
  float wi[3];
  #pragma unroll
  for (int i = 0; i < 3; ++i) wi[i] = eWih[jj * 3 + i];

  __syncthreads();

  int cur = 0;
  float hv[2];
  // ======================= encoder: 64 steps, 1 barrier/step =======================
  for (int t = 0; t < TSTEPS; ++t) {
    f32x4 acc0;
    #pragma unroll
    for (int reg = 0; reg < 2; ++reg) {
      const int r = l4 * 4 + reg;
      const f32x4 xv = *(const f32x4*)&x_lds[r * XROWSTRIDE + t * 4];
      acc0[reg] = bias + wi[0] * xv[0] + wi[1] * xv[1] + wi[2] * xv[2];
    }
    acc0[2] = bias; acc0[3] = bias;   // garbage rows: finite, never read
    const int nxt = cur ^ 1;
    rnn_step(h_hi[cur], h_lo[cur], h_hi[nxt], h_lo[nxt], whi, wlo,
             acc0, l4, ln, jj, hv);
    cur = nxt;
    __syncthreads();
  }

  // ======================= decoder setup =======================
  #pragma unroll
  for (int kt = 0; kt < 4; ++kt) {
    const float* p = dWhh + jj * H + kt * 32 + l4 * 8;
    split_frag(*(const f32x4*)p, *(const f32x4*)(p + 4), whi[kt], wlo[kt]);
  }
  bias = dbih[jj] + dbhh[jj];
  #pragma unroll
  for (int i = 0; i < 3; ++i) wi[i] = dWih[jj * 3 + i];
  float fw[3];
  #pragma unroll
  for (int o = 0; o < 3; ++o) fw[o] = fcW[o * H + jj];
  if (tid < 48) {                       // all 16 LDS rows (dups finite)
    int r = tid / 3, i = tid - 3 * (tid / 3);
    inp_lds[r][i] = x_lds[r * XROWSTRIDE + 63 * 4 + i];
  }
  __syncthreads();

  // ---- decoder step 0 (raw dWhh + real input) ----
  {
    f32x4 acc0;
    #pragma unroll
    for (int reg = 0; reg < 2; ++reg) {
      const int r = l4 * 4 + reg;
      acc0[reg] = bias + wi[0] * inp_lds[r][0] + wi[1] * inp_lds[r][1]
                       + wi[2] * inp_lds[r][2];
    }
    acc0[2] = bias; acc0[3] = bias;
    const int nxt = cur ^ 1;
    rnn_step(h_hi[cur], h_lo[cur], h_hi[nxt], h_lo[nxt], whi, wlo,
             acc0, l4, ln, jj, hv);
    float pp[2][3];
    #pragma unroll
    for (int reg = 0; reg < 2; ++reg)
      #pragma unroll
      for (int o = 0; o < 3; ++o)
        pp[reg][o] = fw[o] * hv[reg];
    #pragma unroll
    for (int m = 1; m <= 8; m <<= 1)
      #pragma unroll
      for (int reg = 0; reg < 2; ++reg)
        #pragma unroll
        for (int o = 0; o < 3; ++o)
          pp[reg][o] += __shfl_xor(pp[reg][o], m, 64);
    if (ln == 0)
      #pragma unroll
      for (int reg = 0; reg < 2; ++reg)
        #pragma unroll
        for (int o = 0; o < 3; ++o)
          part[0][w][l4 * 4 + reg][o] = pp[reg][o];
    cur = nxt;
    __syncthreads();
    if (tid < 24) {
      int r8 = tid / 3, o = tid - 3 * (tid / 3);
      int lr = (r8 >> 1) * 4 + (r8 & 1);
      float pr = fcb[o];
      #pragma unroll
      for (int ww = 0; ww < NWAVE; ++ww) pr += part[0][ww][lr][o];
      out[((size_t)(r0 + r8) * PRED + 0) * 3 + o] = pr;
    }
  }

  // ---- fold feedback: W' = dWhh + dWih@fcW ; bias' = bias + dWih@fcb ----
  #pragma unroll
  for (int kt = 0; kt < 4; ++kt) {
    const int kb = kt * 32 + l4 * 8;
    f32x4 a = *(const f32x4*)(dWhh + jj * H + kb);
    f32x4 b = *(const f32x4*)(dWhh + jj * H + kb + 4);
    #pragma unroll
    for (int o = 0; o < 3; ++o) {
      const f32x4 fa = *(const f32x4*)(fcW + o * H + kb);
      const f32x4 fb = *(const f32x4*)(fcW + o * H + kb + 4);
      #pragma unroll
      for (int e = 0; e < 4; ++e) {
        a[e] += wi[o] * fa[e];
        b[e] += wi[o] * fb[e];
      }
    }
    split_frag(a, b, whi[kt], wlo[kt]);
  }
  float biasp = bias + wi[0] * fcb[0] + wi[1] * fcb[1] + wi[2] * fcb[2];

  // ======================= decoder steps 1..31 =======================
  for (int s = 1; s < PRED; ++s) {
    f32x4 acc0 = {biasp, biasp, biasp, biasp};
    const int nxt = cur ^ 1;
    rnn_step(h_hi[cur], h_lo[cur], h_hi[nxt], h_lo[nxt], whi, wlo,
             acc0, l4, ln, jj, hv);
    float pp[2][3];
    #pragma unroll
    for (int reg = 0; reg < 2; ++reg)
      #pragma unroll
      for (int o = 0; o < 3; ++o)
        pp[reg][o] = fw[o] * hv[reg];
    #pragma unroll
    for (int m = 1; m <= 8; m <<= 1)
      #pragma unroll
      for (int reg = 0; reg < 2; ++reg)
        #pragma unroll
        for (int o = 0; o < 3; ++o)
          pp[reg][o] += __shfl_xor(pp[reg][o], m, 64);
    if (ln == 0)
      #pragma unroll
      for (int reg = 0; reg < 2; ++reg)
        #pragma unroll
        for (int o = 0; o < 3; ++o)
          part[s & 1][w][l4 * 4 + reg][o] = pp[reg][o];
    cur = nxt;
    __syncthreads();
    if (tid < 24) {
      int r8 = tid / 3, o = tid - 3 * (tid / 3);
      int lr = (r8 >> 1) * 4 + (r8 & 1);
      float pr = fcb[o];
      #pragma unroll
      for (int ww = 0; ww < NWAVE; ++ww) pr += part[s & 1][ww][lr][o];
      out[((size_t)(r0 + r8) * PRED + s) * 3 + o] = pr;
    }
  }
}

extern "C" void kernel_launch(void* const* d_in, const int* in_sizes, int n_in,
                              void* d_out, int out_size, void* d_ws, size_t ws_size,
                              hipStream_t stream) {
  (void)in_sizes; (void)n_in; (void)out_size; (void)d_ws; (void)ws_size;
  const float* x    = (const float*)d_in[0];
  const float* eWih = (const float*)d_in[1];
  const float* eWhh = (const float*)d_in[2];
  const float* ebih = (const float*)d_in[3];
  const float* ebhh = (const float*)d_in[4];
  const float* dWih = (const float*)d_in[5];
  const float* dWhh = (const float*)d_in[6];
  const float* dbih = (const float*)d_in[7];
  const float* dbhh = (const float*)d_in[8];
  const float* fcW  = (const float*)d_in[9];
  const float* fcb  = (const float*)d_in[10];
  float* out = (float*)d_out;
  traj_kernel<<<dim3(512), dim3(512), 0, stream>>>(
      x, eWih, eWhh, ebih, ebhh, dWih, dWhh, dbih, dbhh, fcW, fcb, out);
}

// Round 5
// 164.396 us; speedup vs baseline: 1.1696x; 1.1696x over previous
//
#include <hip/hip_runtime.h>

typedef short short8 __attribute__((ext_vector_type(8)));
typedef float f32x4 __attribute__((ext_vector_type(4)));

#define H 128
#define NB 8            // real batch rows per block
#define TSTEPS 64
#define PRED 32
#define XSTRIDE 260     // 64*4 + 4 pad floats

// MFMA D rows are l4*4+reg; regs {0,1} are the real rows (LDS rows
// {0,1,4,5,8,9,12,13}); real batch row for reg in {0,1} is g = l4*2+reg.
// Garbage LDS rows stay finite forever and are never read back as real data.

static __device__ __forceinline__ unsigned short bf16_rne(float f) {
  unsigned u = __builtin_bit_cast(unsigned, f);
  u += 0x7fffu + ((u >> 16) & 1u);
  return (unsigned short)(u >> 16);
}
static __device__ __forceinline__ float bf16_f(unsigned short s) {
  unsigned u = ((unsigned)s) << 16;
  return __builtin_bit_cast(float, u);
}
// R2's tanh (verified 4.88e-4 end-to-end). Do NOT swap for raw v_exp/v_rcp —
// that variant cost 43x accuracy over the 96-step recurrence (R3 post-mortem).
static __device__ __forceinline__ float tanh_fast(float v) {
  v = fminf(9.0f, fmaxf(-9.0f, v));
  float e = __expf(2.0f * v);
  return __fdividef(e - 1.0f, e + 1.0f);
}

static __device__ __forceinline__ void split_frag(const f32x4& a, const f32x4& b,
                                                  short8& hi, short8& lo) {
  #pragma unroll
  for (int e = 0; e < 4; ++e) {
    unsigned short h1 = bf16_rne(a[e]);
    hi[e] = (short)h1;
    lo[e] = (short)bf16_rne(a[e] - bf16_f(h1));
    unsigned short h2 = bf16_rne(b[e]);
    hi[e + 4] = (short)h2;
    lo[e + 4] = (short)bf16_rne(b[e] - bf16_f(h2));
  }
}

__global__ __launch_bounds__(512, 4) void traj_kernel(
    const float* __restrict__ x,
    const float* __restrict__ eWih, const float* __restrict__ eWhh,
    const float* __restrict__ ebih, const float* __restrict__ ebhh,
    const float* __restrict__ dWih, const float* __restrict__ dWhh,
    const float* __restrict__ dbih, const float* __restrict__ dbhh,
    const float* __restrict__ fcW, const float* __restrict__ fcb,
    float* __restrict__ out)
{
  __shared__ __align__(16) float x_lds[16 * XSTRIDE];   // 16.6 KB
  __shared__ __align__(16) short h_hi0[16 * H], h_lo0[16 * H];
  __shared__ __align__(16) short h_hi1[16 * H], h_lo1[16 * H];
  __shared__ float inp_lds[16][4];

  const int tid = threadIdx.x;
  const int lane = tid & 63;
  const int w = tid >> 6;
  const int l4 = lane >> 4;
  const int ln = lane & 15;
  const int r0 = blockIdx.x * NB;
  const int jj = w * 16 + ln;

  // ---- stage x: 16 LDS rows (real rows + duplicates for garbage rows) ----
  #pragma unroll
  for (int s = 0; s < 6; ++s) {
    int flat = tid + s * 512;          // = ldsrow*192 + rem
    int r = flat / 192;
    int rem = flat - r * 192;
    int t = rem / 3;
    int i = rem - t * 3;
    int g = (r >> 2) * 2 + (r & 1);
    x_lds[r * XSTRIDE + t * 4 + i] = x[(size_t)(r0 + g) * 192 + rem];
  }
  // ---- zero both h buffers (garbage rows must stay finite forever) ----
  #pragma unroll
  for (int s = 0; s < 4; ++s) {
    h_hi0[tid + s * 512] = 0; h_hi1[tid + s * 512] = 0;
    h_lo0[tid + s * 512] = 0; h_lo1[tid + s * 512] = 0;
  }

  // ---- encoder weights (row jj of eWhh), split hi/lo ----
  short8 whi[4], wlo[4];
  #pragma unroll
  for (int kt = 0; kt < 4; ++kt) {
    const float* p = eWhh + jj * H + kt * 32 + l4 * 8;
    split_frag(*(const f32x4*)p, *(const f32x4*)(p + 4), whi[kt], wlo[kt]);
  }
  float bias = ebih[jj] + ebhh[jj];
  float wi[3];
  #pragma unroll
  for (int i = 0; i < 3; ++i) wi[i] = eWih[jj * 3 + i];

  // ---- loop-invariant LDS offsets (hoisted once) ----
  int roff[4];
  #pragma unroll
  for (int kt = 0; kt < 4; ++kt)
    roff[kt] = ln * H + ((((kt << 2) + l4) ^ ln) << 3);
  const int rr0 = l4 * 4, rr1 = l4 * 4 + 1;
  const int wo0 = rr0 * H + (((jj >> 3) ^ rr0) << 3) + (jj & 7);
  const int wo1 = rr1 * H + (((jj >> 3) ^ rr1) << 3) + (jj & 7);
  const int xb0 = rr0 * XSTRIDE, xb1 = rr1 * XSTRIDE;

  auto load_frags = [&](const short* __restrict__ hh, const short* __restrict__ hl,
                        short8* ah, short8* al) {
    #pragma unroll
    for (int kt = 0; kt < 4; ++kt) {
      ah[kt] = *(const short8*)&hh[roff[kt]];
      al[kt] = *(const short8*)&hl[roff[kt]];
    }
  };
  auto rnn_core = [&](const short8* ah, const short8* al, f32x4 acc0,
                      short* __restrict__ wh, short* __restrict__ wl) {
    f32x4 accb = {0.f, 0.f, 0.f, 0.f};
    f32x4 accc = {0.f, 0.f, 0.f, 0.f};
    #pragma unroll
    for (int kt = 0; kt < 4; ++kt) {   // 3 independent 4-deep MFMA chains
      acc0 = __builtin_amdgcn_mfma_f32_16x16x32_bf16(ah[kt], whi[kt], acc0, 0, 0, 0);
      accb = __builtin_amdgcn_mfma_f32_16x16x32_bf16(ah[kt], wlo[kt], accb, 0, 0, 0);
      accc = __builtin_amdgcn_mfma_f32_16x16x32_bf16(al[kt], whi[kt], accc, 0, 0, 0);
    }
    #pragma unroll
    for (int reg = 0; reg < 2; ++reg) {  // real rows only
      float v = tanh_fast(acc0[reg] + accb[reg] + accc[reg]);
      unsigned short p = bf16_rne(v);
      const int wo = reg ? wo1 : wo0;
      wh[wo] = (short)p;
      wl[wo] = (short)bf16_rne(v - bf16_f(p));
    }
  };

  __syncthreads();

  // ======================= encoder: 64 steps, unrolled x2 =======================
  for (int t = 0; t < TSTEPS; t += 2) {
    {
      short8 ah[4], al[4];
      load_frags(h_hi0, h_lo0, ah, al);
      f32x4 a;
      const f32x4 x0 = *(const f32x4*)&x_lds[xb0 + t * 4];
      const f32x4 x1 = *(const f32x4*)&x_lds[xb1 + t * 4];
      a[0] = bias + wi[0] * x0[0] + wi[1] * x0[1] + wi[2] * x0[2];
      a[1] = bias + wi[0] * x1[0] + wi[1] * x1[1] + wi[2] * x1[2];
      a[2] = bias; a[3] = bias;
      rnn_core(ah, al, a, h_hi1, h_lo1);
    }
    __syncthreads();
    {
      short8 ah[4], al[4];
      load_frags(h_hi1, h_lo1, ah, al);
      f32x4 a;
      const f32x4 x0 = *(const f32x4*)&x_lds[xb0 + (t + 1) * 4];
      const f32x4 x1 = *(const f32x4*)&x_lds[xb1 + (t + 1) * 4];
      a[0] = bias + wi[0] * x0[0] + wi[1] * x0[1] + wi[2] * x0[2];
      a[1] = bias + wi[0] * x1[0] + wi[1] * x1[1] + wi[2] * x1[2];
      a[2] = bias; a[3] = bias;
      rnn_core(ah, al, a, h_hi0, h_lo0);
    }
    __syncthreads();
  }
  // h_enc now in h_hi0/h_lo0.

  // ======================= decoder setup =======================
  #pragma unroll
  for (int kt = 0; kt < 4; ++kt) {
    const float* p = dWhh + jj * H + kt * 32 + l4 * 8;
    split_frag(*(const f32x4*)p, *(const f32x4*)(p + 4), whi[kt], wlo[kt]);
  }
  bias = dbih[jj] + dbhh[jj];
  #pragma unroll
  for (int i = 0; i < 3; ++i) wi[i] = dWih[jj * 3 + i];

  // fc head as MFMA B-fragments: B[k][n=o] = fcW[o][k], lanes ln>=3 zero.
  short8 fhi[4];
  #pragma unroll
  for (int kt = 0; kt < 4; ++kt) {
    f32x4 a = {0.f, 0.f, 0.f, 0.f}, b = {0.f, 0.f, 0.f, 0.f};
    if (ln < 3) {
      const float* p = fcW + ln * H + kt * 32 + l4 * 8;
      a = *(const f32x4*)p;
      b = *(const f32x4*)(p + 4);
    }
    short8 hi;
    #pragma unroll
    for (int e = 0; e < 4; ++e) {
      hi[e] = (short)bf16_rne(a[e]);
      hi[e + 4] = (short)bf16_rne(b[e]);
    }
    fhi[kt] = hi;
  }
  const float fcbl = (ln < 3) ? fcb[ln] : 0.f;

  if (tid < 48) {                       // all 16 LDS rows (dups finite)
    int r = tid / 3, i = tid - 3 * (tid / 3);
    inp_lds[r][i] = x_lds[r * XSTRIDE + 63 * 4 + i];
  }
  __syncthreads();

  // ---- decoder step 0 (raw dWhh + real input) ----
  {
    short8 ah[4], al[4];
    load_frags(h_hi0, h_lo0, ah, al);
    f32x4 a;
    a[0] = bias + wi[0] * inp_lds[rr0][0] + wi[1] * inp_lds[rr0][1]
                + wi[2] * inp_lds[rr0][2];
    a[1] = bias + wi[0] * inp_lds[rr1][0] + wi[1] * inp_lds[rr1][1]
                + wi[2] * inp_lds[rr1][2];
    a[2] = bias; a[3] = bias;
    rnn_core(ah, al, a, h_hi1, h_lo1);
  }
  __syncthreads();

  // ---- fold feedback: W' = dWhh + dWih@fcW ; bias' = bias + dWih@fcb ----
  #pragma unroll
  for (int kt = 0; kt < 4; ++kt) {
    const int kb = kt * 32 + l4 * 8;
    f32x4 a = *(const f32x4*)(dWhh + jj * H + kb);
    f32x4 b = *(const f32x4*)(dWhh + jj * H + kb + 4);
    #pragma unroll
    for (int o = 0; o < 3; ++o) {
      const f32x4 fa = *(const f32x4*)(fcW + o * H + kb);
      const f32x4 fb = *(const f32x4*)(fcW + o * H + kb + 4);
      #pragma unroll
      for (int e = 0; e < 4; ++e) {
        a[e] += wi[o] * fa[e];
        b[e] += wi[o] * fb[e];
      }
    }
    split_frag(a, b, whi[kt], wlo[kt]);
  }
  const float biasp = bias + wi[0] * fcb[0] + wi[1] * fcb[1] + wi[2] * fcb[2];
  const f32x4 accd = {biasp, biasp, biasp, biasp};

  // ======================= decoder steps 1..31: 1 barrier/step =======================
  const short* rdh = h_hi1; const short* rdl = h_lo1;
  short* wrh = h_hi0;       short* wrl = h_lo0;
  for (int s = 1; s < PRED; ++s) {
    short8 ah[4], al[4];
    load_frags(rdh, rdl, ah, al);
    rnn_core(ah, al, accd, wrh, wrl);
    // pred[s-1] = fcW·h[s-1] + fcb via MFMA on one rotating wave (off-path)
    if (w == (s & 7)) {
      f32x4 f0 = {0.f, 0.f, 0.f, 0.f};
      f32x4 f1 = {0.f, 0.f, 0.f, 0.f};
      #pragma unroll
      for (int kt = 0; kt < 4; ++kt) {
        f0 = __builtin_amdgcn_mfma_f32_16x16x32_bf16(ah[kt], fhi[kt], f0, 0, 0, 0);
        f1 = __builtin_amdgcn_mfma_f32_16x16x32_bf16(al[kt], fhi[kt], f1, 0, 0, 0);
      }
      if (ln < 3) {
        out[((size_t)(r0 + l4 * 2 + 0) * PRED + (s - 1)) * 3 + ln] =
            f0[0] + f1[0] + fcbl;
        out[((size_t)(r0 + l4 * 2 + 1) * PRED + (s - 1)) * 3 + ln] =
            f0[1] + f1[1] + fcbl;
      }
    }
    __syncthreads();
    const short* th = rdh; rdh = wrh; wrh = (short*)th;
    const short* tl = rdl; rdl = wrl; wrl = (short*)tl;
  }
  // ---- drain: pred[31] from final h ----
  if (w == 0) {
    short8 ah[4], al[4];
    load_frags(rdh, rdl, ah, al);
    f32x4 f0 = {0.f, 0.f, 0.f, 0.f};
    f32x4 f1 = {0.f, 0.f, 0.f, 0.f};
    #pragma unroll
    for (int kt = 0; kt < 4; ++kt) {
      f0 = __builtin_amdgcn_mfma_f32_16x16x32_bf16(ah[kt], fhi[kt], f0, 0, 0, 0);
      f1 = __builtin_amdgcn_mfma_f32_16x16x32_bf16(al[kt], fhi[kt], f1, 0, 0, 0);
    }
    if (ln < 3) {
      out[((size_t)(r0 + l4 * 2 + 0) * PRED + (PRED - 1)) * 3 + ln] =
          f0[0] + f1[0] + fcbl;
      out[((size_t)(r0 + l4 * 2 + 1) * PRED + (PRED - 1)) * 3 + ln] =
          f0[1] + f1[1] + fcbl;
    }
  }
}

extern "C" void kernel_launch(void* const* d_in, const int* in_sizes, int n_in,
                              void* d_out, int out_size, void* d_ws, size_t ws_size,
                              hipStream_t stream) {
  (void)in_sizes; (void)n_in; (void)out_size; (void)d_ws; (void)ws_size;
  const float* x    = (const float*)d_in[0];
  const float* eWih = (const float*)d_in[1];
  const float* eWhh = (const float*)d_in[2];
  const float* ebih = (const float*)d_in[3];
  const float* ebhh = (const float*)d_in[4];
  const float* dWih = (const float*)d_in[5];
  const float* dWhh = (const float*)d_in[6];
  const float* dbih = (const float*)d_in[7];
  const float* dbhh = (const float*)d_in[8];
  const float* fcW  = (const float*)d_in[9];
  const float* fcb  = (const float*)d_in[10];
  float* out = (float*)d_out;
  traj_kernel<<<dim3(512), dim3(512), 0, stream>>>(
      x, eWih, eWhh, ebih, ebhh, dWih, dWhh, dbih, dbhh, fcW, fcb, out);
}